// Round 16
// baseline (122.876 us; speedup 1.0000x reference)
//
#include <hip/hip_runtime.h>

// VQ-VAE VectorQuantizer forward, MI355X (gfx950)
// inputs:  d_in[0] = inputs  [64,32,32,64] f32  (N=65536 rows, D=64)
//          d_in[1] = context [1] (unused)
//          d_in[2] = embeddings [64,512] f32    (D=64, K=512)
// out (flat f32): quantized[4194304] | loss[1] | perplexity[1] |
//   encodings[33554432] | encoding_indices[65536] | distances[33554432]

#define NROWS 65536
#define DIM 64
#define KCODES 512
#define ROWS_PER_BLOCK 128
#define NBLOCKS (NROWS / ROWS_PER_BLOCK)   // 512
#define RPT 8

#define QUANT_OFF 0ull
#define LOSS_OFF  4194304ull
#define PERP_OFF  4194305ull
#define ENC_OFF   4194306ull
#define IDX_OFF   37748738ull
#define DIST_OFF  37814274ull

typedef float f32x4 __attribute__((ext_vector_type(4)));
typedef float f32x2 __attribute__((ext_vector_type(2)));

// packed 2xf32 FMA; src1 broadcast from LO or HI half via op_sel
#define PKFMA_LO(a, e, x) \
    asm("v_pk_fma_f32 %0, %1, %2, %0 op_sel:[0,0,0] op_sel_hi:[1,0,1]" \
        : "+v"(a) : "v"(e), "v"(x))
#define PKFMA_HI(a, e, x) \
    asm("v_pk_fma_f32 %0, %1, %2, %0 op_sel:[0,1,0] op_sel_hi:[1,1,1]" \
        : "+v"(a) : "v"(e), "v"(x))

// ---- K0: transpose E[64][512] -> ET[512][64] in workspace (runs once)
__global__ __launch_bounds__(64) void vq_transpose(
    const float* __restrict__ emb, float* __restrict__ et)
{
    const int t = blockIdx.x * 64 + threadIdx.x;   // one k per thread
    f32x4* et4 = (f32x4*)et;                       // [512][16]
#pragma unroll
    for (int dq = 0; dq < 16; ++dq) {
        f32x4 v;
        v.x = emb[(dq * 4 + 0) * KCODES + t];      // coalesced per d
        v.y = emb[(dq * 4 + 1) * KCODES + t];
        v.z = emb[(dq * 4 + 2) * KCODES + t];
        v.w = emb[(dq * 4 + 3) * KCODES + t];
        et4[t * 16 + dq] = v;
    }
}

// ---- K1: main fused kernel. Encodings are PRE-ZEROED by hipMemsetAsync
//      (6.8 TB/s fill path); only the 1.0 winner dword is written here.
__global__ __launch_bounds__(512, 4) void vq_main(
    const float* __restrict__ inp, const float* __restrict__ emb,
    const float* __restrict__ et,
    float* __restrict__ out, int* __restrict__ hist,
    float* __restrict__ loss_part)
{
    __shared__ f32x4 s_X[ROWS_PER_BLOCK * 16];    // 32 KB [row][dq]
    __shared__ float s_sumx2[ROWS_PER_BLOCK];
    __shared__ float s_loss[8];

    const int tid  = threadIdx.x;
    const int w    = tid >> 6;                    // wave 0..7
    const int lane = tid & 63;
    const int rbase = blockIdx.x * ROWS_PER_BLOCK;
    // lane owns k = h*256 + lane*4 + j  (h=0,1; j=0..3)

    // ---- stage all 128 rows of x -> LDS (coalesced b128, linear) ----
    {
        const f32x4* inp4 = (const f32x4*)inp;
#pragma unroll
        for (int i = 0; i < 4; ++i)
            s_X[i * 512 + tid] = inp4[(size_t)blockIdx.x * 2048 + i * 512 + tid];
    }
    __syncthreads();   // the ONLY barrier before the store streams start

    // ---- per-row ||x||^2 for THIS wave's 16 rows (no further barrier) ----
    {
        const int row_l = w * 16 + (lane >> 2);
        const int q = lane & 3;
        float p = 0.f;
#pragma unroll
        for (int j = 0; j < 4; ++j) {
            const f32x4 v = s_X[row_l * 16 + q * 4 + j];
            p = fmaf(v.x, v.x, p); p = fmaf(v.y, v.y, p);
            p = fmaf(v.z, v.z, p); p = fmaf(v.w, v.w, p);
        }
        p += __shfl_xor(p, 1);
        p += __shfl_xor(p, 2);
        if (q == 0) s_sumx2[row_l] = p;           // same wave reads it later
    }

    f32x4 sume2_0 = {0.f, 0.f, 0.f, 0.f};
    f32x4 sume2_1 = {0.f, 0.f, 0.f, 0.f};
    float loss_acc = 0.f;

    const float* ebase = emb + lane * 4;
    const f32x4* et4 = (const f32x4*)et;

#pragma unroll 1
    for (int g = 0; g < 2; ++g) {
        const int rl0 = w * 16 + g * RPT;         // block-local row base

        // acc[row][h][pair]: pair0 = {k0,k1}, pair1 = {k2,k3}
        f32x2 acc[RPT][2][2];
#pragma unroll
        for (int r = 0; r < RPT; ++r)
#pragma unroll
            for (int h = 0; h < 2; ++h) {
                acc[r][h][0] = (f32x2){0.f, 0.f};
                acc[r][h][1] = (f32x2){0.f, 0.f};
            }

#pragma unroll 1
        for (int dq = 0; dq < 16; ++dq) {
            f32x4 e0[4], e1[4];
#pragma unroll
            for (int sub = 0; sub < 4; ++sub) {
                e0[sub] = *(const f32x4*)(ebase + (dq * 4 + sub) * KCODES);
                e1[sub] = *(const f32x4*)(ebase + (dq * 4 + sub) * KCODES + 256);
            }
            if (g == 0) {                         // fold ||e||^2 into group 0
#pragma unroll
                for (int sub = 0; sub < 4; ++sub) {
                    sume2_0 = sume2_0 + e0[sub] * e0[sub];
                    sume2_1 = sume2_1 + e1[sub] * e1[sub];
                }
            }
            // pair views of e (subregister extraction, no movs)
            f32x2 e0lo[4], e0hi[4], e1lo[4], e1hi[4];
#pragma unroll
            for (int sub = 0; sub < 4; ++sub) {
                e0lo[sub] = __builtin_shufflevector(e0[sub], e0[sub], 0, 1);
                e0hi[sub] = __builtin_shufflevector(e0[sub], e0[sub], 2, 3);
                e1lo[sub] = __builtin_shufflevector(e1[sub], e1[sub], 0, 1);
                e1hi[sub] = __builtin_shufflevector(e1[sub], e1[sub], 2, 3);
            }
#pragma unroll
            for (int r = 0; r < RPT; ++r) {
                const f32x4 xv = s_X[(rl0 + r) * 16 + dq];   // DS broadcast
                const f32x2 xlo = __builtin_shufflevector(xv, xv, 0, 1);
                const f32x2 xhi = __builtin_shufflevector(xv, xv, 2, 3);
                PKFMA_LO(acc[r][0][0], e0lo[0], xlo);
                PKFMA_LO(acc[r][0][1], e0hi[0], xlo);
                PKFMA_LO(acc[r][1][0], e1lo[0], xlo);
                PKFMA_LO(acc[r][1][1], e1hi[0], xlo);
                PKFMA_HI(acc[r][0][0], e0lo[1], xlo);
                PKFMA_HI(acc[r][0][1], e0hi[1], xlo);
                PKFMA_HI(acc[r][1][0], e1lo[1], xlo);
                PKFMA_HI(acc[r][1][1], e1hi[1], xlo);
                PKFMA_LO(acc[r][0][0], e0lo[2], xhi);
                PKFMA_LO(acc[r][0][1], e0hi[2], xhi);
                PKFMA_LO(acc[r][1][0], e1lo[2], xhi);
                PKFMA_LO(acc[r][1][1], e1hi[2], xhi);
                PKFMA_HI(acc[r][0][0], e0lo[3], xhi);
                PKFMA_HI(acc[r][0][1], e0hi[3], xhi);
                PKFMA_HI(acc[r][1][0], e1lo[3], xhi);
                PKFMA_HI(acc[r][1][1], e1hi[3], xhi);
            }
        }

        // ---- epilogue: distances, ballot argmin, stores ----
#pragma unroll
        for (int r = 0; r < RPT; ++r) {
            const int row = rbase + rl0 + r;
            const float sx2 = s_sumx2[rl0 + r];

            const f32x4 a0 = {acc[r][0][0].x, acc[r][0][0].y,
                              acc[r][0][1].x, acc[r][0][1].y};
            const f32x4 a1 = {acc[r][1][0].x, acc[r][1][0].y,
                              acc[r][1][1].x, acc[r][1][1].y};
            const f32x4 dd0 = (sume2_0 + sx2) + (-2.f) * a0;
            const f32x4 dd1 = (sume2_1 + sx2) + (-2.f) * a1;

            f32x4* dp = (f32x4*)(out + DIST_OFF) + (size_t)row * 128;
            dp[lane]      = dd0;
            dp[64 + lane] = dd1;

            // wave min (6 shuffles), then exact smallest-k via 8 ballots
            float fd = fminf(fminf(fminf(dd0.x, dd0.y), fminf(dd0.z, dd0.w)),
                             fminf(fminf(dd1.x, dd1.y), fminf(dd1.z, dd1.w)));
#pragma unroll
            for (int off = 32; off; off >>= 1)
                fd = fminf(fd, __shfl_xor(fd, off));

            int c2 = 0x7fffffff;
            unsigned long long m;
            m = __ballot(dd0.x == fd);
            if (m) { int c = (int)__builtin_ctzll(m) * 4 + 0;       c2 = c < c2 ? c : c2; }
            m = __ballot(dd0.y == fd);
            if (m) { int c = (int)__builtin_ctzll(m) * 4 + 1;       c2 = c < c2 ? c : c2; }
            m = __ballot(dd0.z == fd);
            if (m) { int c = (int)__builtin_ctzll(m) * 4 + 2;       c2 = c < c2 ? c : c2; }
            m = __ballot(dd0.w == fd);
            if (m) { int c = (int)__builtin_ctzll(m) * 4 + 3;       c2 = c < c2 ? c : c2; }
            m = __ballot(dd1.x == fd);
            if (m) { int c = (int)__builtin_ctzll(m) * 4 + 0 + 256; c2 = c < c2 ? c : c2; }
            m = __ballot(dd1.y == fd);
            if (m) { int c = (int)__builtin_ctzll(m) * 4 + 1 + 256; c2 = c < c2 ? c : c2; }
            m = __ballot(dd1.z == fd);
            if (m) { int c = (int)__builtin_ctzll(m) * 4 + 2 + 256; c2 = c < c2 ? c : c2; }
            m = __ballot(dd1.w == fd);
            if (m) { int c = (int)__builtin_ctzll(m) * 4 + 3 + 256; c2 = c < c2 ? c : c2; }

            // encodings: region pre-zeroed by memset; write ONLY the winner
            if (lane == 0)
                out[ENC_OFF + (size_t)row * KCODES + c2] = 1.f;

            // quantized row from pre-transposed ET: 16 lanes x f32x4 (L2-hot)
            if (lane < 16) {
                const f32x4 q = et4[c2 * 16 + lane];
                ((f32x4*)(out + QUANT_OFF + (size_t)row * DIM))[lane] = q;
            }

            if (lane == 0) {
                out[IDX_OFF + row] = (float)c2;
                atomicAdd(&hist[c2], 1);
                loss_acc += fd;                   // sum_d(q-x)^2 == min dist
            }
        }
    }

    // ---- loss: deterministic per-block partial ----
    if (lane == 0) s_loss[w] = loss_acc;
    __syncthreads();
    if (tid == 0) {
        float s = 0.f;
#pragma unroll
        for (int i = 0; i < 8; ++i) s += s_loss[i];
        loss_part[blockIdx.x] = s;
    }
}

__global__ __launch_bounds__(512) void vq_final(
    const int* __restrict__ hist, const float* __restrict__ loss_part,
    float* __restrict__ out)
{
    __shared__ float s_red[8];
    __shared__ float s_red2[8];
    const int tid = threadIdx.x;
    const int w = tid >> 6, lane = tid & 63;

    float p = (float)hist[tid] * (1.f / 65536.f);
    float t = p * logf(p + 1e-10f);   // p==0 -> 0
    float l = loss_part[tid];         // 512 partials, fixed order
#pragma unroll
    for (int off = 32; off; off >>= 1) {
        t += __shfl_xor(t, off);
        l += __shfl_xor(l, off);
    }
    if (lane == 0) { s_red[w] = t; s_red2[w] = l; }
    __syncthreads();
    if (tid == 0) {
        float s = 0.f, ls = 0.f;
#pragma unroll
        for (int i = 0; i < 8; ++i) { s += s_red[i]; ls += s_red2[i]; }
        out[PERP_OFF] = expf(-s);
        // loss = (1 + 0.25) * mean((q - x)^2) over 4194304 elements
        out[LOSS_OFF] = ls * (1.25f / 4194304.f);
    }
}

extern "C" void kernel_launch(void* const* d_in, const int* in_sizes, int n_in,
                              void* d_out, int out_size, void* d_ws, size_t ws_size,
                              hipStream_t stream) {
    const float* inp = (const float*)d_in[0];
    const float* emb = (const float*)d_in[2];
    float* out = (float*)d_out;
    int*   hist      = (int*)d_ws;                     // 512 ints   @ 0
    float* loss_part = (float*)((char*)d_ws + 2048);   // 512 floats @ 2048
    float* et        = (float*)((char*)d_ws + 8192);   // 128 KB ET  @ 8192

    // zero the 128 MB encodings region on the fill path (~19 us @ 6.8 TB/s);
    // vq_main then writes only the 65536 winner dwords.
    (void)hipMemsetAsync(out + ENC_OFF, 0,
                         (size_t)NROWS * KCODES * sizeof(float), stream);
    (void)hipMemsetAsync(d_ws, 0, 2048, stream);       // hist
    vq_transpose<<<dim3(8), dim3(64), 0, stream>>>(emb, et);
    vq_main<<<dim3(NBLOCKS), dim3(512), 0, stream>>>(
        inp, emb, et, out, hist, loss_part);
    vq_final<<<dim3(1), dim3(512), 0, stream>>>(hist, loss_part, out);
}

// Round 17
// 99.125 us; speedup vs baseline: 1.2396x; 1.2396x over previous
//
#include <hip/hip_runtime.h>

// VQ-VAE VectorQuantizer forward, MI355X (gfx950)
// inputs:  d_in[0] = inputs  [64,32,32,64] f32  (N=65536 rows, D=64)
//          d_in[1] = context [1] (unused)
//          d_in[2] = embeddings [64,512] f32    (D=64, K=512)
// out (flat f32): quantized[4194304] | loss[1] | perplexity[1] |
//   encodings[33554432] | encoding_indices[65536] | distances[33554432]

#define NROWS 65536
#define DIM 64
#define KCODES 512
#define ROWS_PER_BLOCK 128
#define NBLOCKS (NROWS / ROWS_PER_BLOCK)   // 512
#define RPT 8

#define QUANT_OFF 0ull
#define LOSS_OFF  4194304ull
#define PERP_OFF  4194305ull
#define ENC_OFF   4194306ull
#define IDX_OFF   37748738ull
#define DIST_OFF  37814274ull

typedef float f32x4 __attribute__((ext_vector_type(4)));
typedef float f32x2 __attribute__((ext_vector_type(2)));

// packed 2xf32 FMA; src1 broadcast from LO or HI half via op_sel
#define PKFMA_LO(a, e, x) \
    asm("v_pk_fma_f32 %0, %1, %2, %0 op_sel:[0,0,0] op_sel_hi:[1,0,1]" \
        : "+v"(a) : "v"(e), "v"(x))
#define PKFMA_HI(a, e, x) \
    asm("v_pk_fma_f32 %0, %1, %2, %0 op_sel:[0,1,0] op_sel_hi:[1,1,1]" \
        : "+v"(a) : "v"(e), "v"(x))

// ---- K0: transpose E -> ET[512][64] AND precompute ||e_k||^2 (once)
__global__ __launch_bounds__(64) void vq_transpose(
    const float* __restrict__ emb, float* __restrict__ et,
    float* __restrict__ se)
{
    const int t = blockIdx.x * 64 + threadIdx.x;   // one k per thread
    f32x4* et4 = (f32x4*)et;                       // [512][16]
    float s = 0.f;
#pragma unroll
    for (int dq = 0; dq < 16; ++dq) {
        f32x4 v;
        v.x = emb[(dq * 4 + 0) * KCODES + t];      // coalesced per d
        v.y = emb[(dq * 4 + 1) * KCODES + t];
        v.z = emb[(dq * 4 + 2) * KCODES + t];
        v.w = emb[(dq * 4 + 3) * KCODES + t];
        et4[t * 16 + dq] = v;
        s = fmaf(v.x, v.x, s); s = fmaf(v.y, v.y, s);
        s = fmaf(v.z, v.z, s); s = fmaf(v.w, v.w, s);
    }
    se[t] = s;
}

// ---- K1: main fused kernel (R15 champion) with unroll-2 dq loop
//      (cross-iteration e-load/FMA overlap) and precomputed ||e||^2.
__global__ __launch_bounds__(512, 4) void vq_main(
    const float* __restrict__ inp, const float* __restrict__ emb,
    const float* __restrict__ et, const float* __restrict__ se,
    float* __restrict__ out, int* __restrict__ hist,
    float* __restrict__ loss_part)
{
    __shared__ f32x4 s_X[ROWS_PER_BLOCK * 16];    // 32 KB [row][dq]
    __shared__ float s_sumx2[ROWS_PER_BLOCK];
    __shared__ float s_loss[8];

    const int tid  = threadIdx.x;
    const int w    = tid >> 6;                    // wave 0..7
    const int lane = tid & 63;
    const int rbase = blockIdx.x * ROWS_PER_BLOCK;
    // lane owns k = h*256 + lane*4 + j  (h=0,1; j=0..3)

    // ---- stage all 128 rows of x -> LDS (coalesced b128, linear) ----
    {
        const f32x4* inp4 = (const f32x4*)inp;
#pragma unroll
        for (int i = 0; i < 4; ++i)
            s_X[i * 512 + tid] = inp4[(size_t)blockIdx.x * 2048 + i * 512 + tid];
    }
    // precomputed ||e||^2 for this lane's 8 k's (two f32x4 loads, L2-hot)
    const f32x4 sume2_0 = ((const f32x4*)se)[lane];
    const f32x4 sume2_1 = ((const f32x4*)se)[64 + lane];
    __syncthreads();   // the ONLY barrier before the store streams start

    // ---- per-row ||x||^2 for THIS wave's 16 rows (no further barrier) ----
    {
        const int row_l = w * 16 + (lane >> 2);
        const int q = lane & 3;
        float p = 0.f;
#pragma unroll
        for (int j = 0; j < 4; ++j) {
            const f32x4 v = s_X[row_l * 16 + q * 4 + j];
            p = fmaf(v.x, v.x, p); p = fmaf(v.y, v.y, p);
            p = fmaf(v.z, v.z, p); p = fmaf(v.w, v.w, p);
        }
        p += __shfl_xor(p, 1);
        p += __shfl_xor(p, 2);
        if (q == 0) s_sumx2[row_l] = p;           // same wave reads it later
    }

    float loss_acc = 0.f;
    const float* ebase = emb + lane * 4;
    const f32x4* et4 = (const f32x4*)et;

#pragma unroll 1
    for (int g = 0; g < 2; ++g) {
        const int rl0 = w * 16 + g * RPT;         // block-local row base

        // acc[row][h][pair]: pair0 = {k0,k1}, pair1 = {k2,k3}
        f32x2 acc[RPT][2][2];
#pragma unroll
        for (int r = 0; r < RPT; ++r)
#pragma unroll
            for (int h = 0; h < 2; ++h) {
                acc[r][h][0] = (f32x2){0.f, 0.f};
                acc[r][h][1] = (f32x2){0.f, 0.f};
            }

#pragma unroll 2
        for (int dq = 0; dq < 16; ++dq) {
            f32x4 e0[4], e1[4];
#pragma unroll
            for (int sub = 0; sub < 4; ++sub) {
                e0[sub] = *(const f32x4*)(ebase + (dq * 4 + sub) * KCODES);
                e1[sub] = *(const f32x4*)(ebase + (dq * 4 + sub) * KCODES + 256);
            }
            // pair views of e (subregister extraction, no movs)
            f32x2 e0lo[4], e0hi[4], e1lo[4], e1hi[4];
#pragma unroll
            for (int sub = 0; sub < 4; ++sub) {
                e0lo[sub] = __builtin_shufflevector(e0[sub], e0[sub], 0, 1);
                e0hi[sub] = __builtin_shufflevector(e0[sub], e0[sub], 2, 3);
                e1lo[sub] = __builtin_shufflevector(e1[sub], e1[sub], 0, 1);
                e1hi[sub] = __builtin_shufflevector(e1[sub], e1[sub], 2, 3);
            }
#pragma unroll
            for (int r = 0; r < RPT; ++r) {
                const f32x4 xv = s_X[(rl0 + r) * 16 + dq];   // DS broadcast
                const f32x2 xlo = __builtin_shufflevector(xv, xv, 0, 1);
                const f32x2 xhi = __builtin_shufflevector(xv, xv, 2, 3);
                PKFMA_LO(acc[r][0][0], e0lo[0], xlo);
                PKFMA_LO(acc[r][0][1], e0hi[0], xlo);
                PKFMA_LO(acc[r][1][0], e1lo[0], xlo);
                PKFMA_LO(acc[r][1][1], e1hi[0], xlo);
                PKFMA_HI(acc[r][0][0], e0lo[1], xlo);
                PKFMA_HI(acc[r][0][1], e0hi[1], xlo);
                PKFMA_HI(acc[r][1][0], e1lo[1], xlo);
                PKFMA_HI(acc[r][1][1], e1hi[1], xlo);
                PKFMA_LO(acc[r][0][0], e0lo[2], xhi);
                PKFMA_LO(acc[r][0][1], e0hi[2], xhi);
                PKFMA_LO(acc[r][1][0], e1lo[2], xhi);
                PKFMA_LO(acc[r][1][1], e1hi[2], xhi);
                PKFMA_HI(acc[r][0][0], e0lo[3], xhi);
                PKFMA_HI(acc[r][0][1], e0hi[3], xhi);
                PKFMA_HI(acc[r][1][0], e1lo[3], xhi);
                PKFMA_HI(acc[r][1][1], e1hi[3], xhi);
            }
        }

        // ---- epilogue: distances, ballot argmin, stores (plain, L2-routed) ----
#pragma unroll
        for (int r = 0; r < RPT; ++r) {
            const int row = rbase + rl0 + r;
            const float sx2 = s_sumx2[rl0 + r];

            const f32x4 a0 = {acc[r][0][0].x, acc[r][0][0].y,
                              acc[r][0][1].x, acc[r][0][1].y};
            const f32x4 a1 = {acc[r][1][0].x, acc[r][1][0].y,
                              acc[r][1][1].x, acc[r][1][1].y};
            const f32x4 dd0 = (sume2_0 + sx2) + (-2.f) * a0;
            const f32x4 dd1 = (sume2_1 + sx2) + (-2.f) * a1;

            f32x4* dp = (f32x4*)(out + DIST_OFF) + (size_t)row * 128;
            dp[lane]      = dd0;
            dp[64 + lane] = dd1;

            // wave min (6 shuffles), then exact smallest-k via 8 ballots
            float fd = fminf(fminf(fminf(dd0.x, dd0.y), fminf(dd0.z, dd0.w)),
                             fminf(fminf(dd1.x, dd1.y), fminf(dd1.z, dd1.w)));
#pragma unroll
            for (int off = 32; off; off >>= 1)
                fd = fminf(fd, __shfl_xor(fd, off));

            int c2 = 0x7fffffff;
            unsigned long long m;
            m = __ballot(dd0.x == fd);
            if (m) { int c = (int)__builtin_ctzll(m) * 4 + 0;       c2 = c < c2 ? c : c2; }
            m = __ballot(dd0.y == fd);
            if (m) { int c = (int)__builtin_ctzll(m) * 4 + 1;       c2 = c < c2 ? c : c2; }
            m = __ballot(dd0.z == fd);
            if (m) { int c = (int)__builtin_ctzll(m) * 4 + 2;       c2 = c < c2 ? c : c2; }
            m = __ballot(dd0.w == fd);
            if (m) { int c = (int)__builtin_ctzll(m) * 4 + 3;       c2 = c < c2 ? c : c2; }
            m = __ballot(dd1.x == fd);
            if (m) { int c = (int)__builtin_ctzll(m) * 4 + 0 + 256; c2 = c < c2 ? c : c2; }
            m = __ballot(dd1.y == fd);
            if (m) { int c = (int)__builtin_ctzll(m) * 4 + 1 + 256; c2 = c < c2 ? c : c2; }
            m = __ballot(dd1.z == fd);
            if (m) { int c = (int)__builtin_ctzll(m) * 4 + 2 + 256; c2 = c < c2 ? c : c2; }
            m = __ballot(dd1.w == fd);
            if (m) { int c = (int)__builtin_ctzll(m) * 4 + 3 + 256; c2 = c < c2 ? c : c2; }

            // encodings one-hot: 2 contiguous f32x4 plain stores
            f32x4* ep = (f32x4*)(out + ENC_OFF) + (size_t)row * 128;
            const int cq = c2 >> 2;
            f32x4 v0 = {0.f, 0.f, 0.f, 0.f};
            f32x4 v1 = {0.f, 0.f, 0.f, 0.f};
            if (cq == lane) {
                v0.x = (c2 & 3) == 0 ? 1.f : 0.f;
                v0.y = (c2 & 3) == 1 ? 1.f : 0.f;
                v0.z = (c2 & 3) == 2 ? 1.f : 0.f;
                v0.w = (c2 & 3) == 3 ? 1.f : 0.f;
            }
            if (cq == 64 + lane) {
                v1.x = (c2 & 3) == 0 ? 1.f : 0.f;
                v1.y = (c2 & 3) == 1 ? 1.f : 0.f;
                v1.z = (c2 & 3) == 2 ? 1.f : 0.f;
                v1.w = (c2 & 3) == 3 ? 1.f : 0.f;
            }
            ep[lane]      = v0;
            ep[64 + lane] = v1;

            // quantized row from pre-transposed ET: 16 lanes x f32x4 (L2-hot)
            if (lane < 16) {
                const f32x4 q = et4[c2 * 16 + lane];
                ((f32x4*)(out + QUANT_OFF + (size_t)row * DIM))[lane] = q;
            }

            if (lane == 0) {
                out[IDX_OFF + row] = (float)c2;
                atomicAdd(&hist[c2], 1);
                loss_acc += fd;                   // sum_d(q-x)^2 == min dist
            }
        }
    }

    // ---- loss: deterministic per-block partial ----
    if (lane == 0) s_loss[w] = loss_acc;
    __syncthreads();
    if (tid == 0) {
        float s = 0.f;
#pragma unroll
        for (int i = 0; i < 8; ++i) s += s_loss[i];
        loss_part[blockIdx.x] = s;
    }
}

__global__ __launch_bounds__(512) void vq_final(
    const int* __restrict__ hist, const float* __restrict__ loss_part,
    float* __restrict__ out)
{
    __shared__ float s_red[8];
    __shared__ float s_red2[8];
    const int tid = threadIdx.x;
    const int w = tid >> 6, lane = tid & 63;

    float p = (float)hist[tid] * (1.f / 65536.f);
    float t = p * logf(p + 1e-10f);   // p==0 -> 0
    float l = loss_part[tid];         // 512 partials, fixed order
#pragma unroll
    for (int off = 32; off; off >>= 1) {
        t += __shfl_xor(t, off);
        l += __shfl_xor(l, off);
    }
    if (lane == 0) { s_red[w] = t; s_red2[w] = l; }
    __syncthreads();
    if (tid == 0) {
        float s = 0.f, ls = 0.f;
#pragma unroll
        for (int i = 0; i < 8; ++i) { s += s_red[i]; ls += s_red2[i]; }
        out[PERP_OFF] = expf(-s);
        // loss = (1 + 0.25) * mean((q - x)^2) over 4194304 elements
        out[LOSS_OFF] = ls * (1.25f / 4194304.f);
    }
}

extern "C" void kernel_launch(void* const* d_in, const int* in_sizes, int n_in,
                              void* d_out, int out_size, void* d_ws, size_t ws_size,
                              hipStream_t stream) {
    const float* inp = (const float*)d_in[0];
    const float* emb = (const float*)d_in[2];
    float* out = (float*)d_out;
    int*   hist      = (int*)d_ws;                     // 512 ints   @ 0
    float* loss_part = (float*)((char*)d_ws + 2048);   // 512 floats @ 2048
    float* et        = (float*)((char*)d_ws + 8192);   // 128 KB ET  @ 8192
    float* se        = (float*)((char*)d_ws + 8192 + 131072);  // 512 floats

    (void)hipMemsetAsync(d_ws, 0, 2048, stream);       // hist only
    vq_transpose<<<dim3(8), dim3(64), 0, stream>>>(emb, et, se);
    vq_main<<<dim3(NBLOCKS), dim3(512), 0, stream>>>(
        inp, emb, et, se, out, hist, loss_part);
    vq_final<<<dim3(1), dim3(512), 0, stream>>>(hist, loss_part, out);
}